// Round 5
// baseline (381.403 us; speedup 1.0000x reference)
//
#include <hip/hip_runtime.h>
#include <stdint.h>

#define M_DIM 8192
#define N_DIM 8192
#define K_DIM 1024
#define BK    128

typedef int int4v __attribute__((ext_vector_type(4)));

// ---- async global->LDS, 16B per lane ----
__device__ __forceinline__ void gload16(const char* g, char* l) {
    __builtin_amdgcn_global_load_lds(
        (__attribute__((address_space(1))) void*)(void*)const_cast<char*>(g),
        (__attribute__((address_space(3))) void*)l,
        16, 0, 0);
}

__device__ __forceinline__ int sat8(int v) {
    v = v > 127 ? 127 : v;
    v = v < -128 ? -128 : v;
    return v;
}

// ---- pack a: int32 [M][K] -> int8 [M][K], 4 elems/thread, fully coalesced ----
__global__ __launch_bounds__(256) void pack_a_kernel(const int* __restrict__ a,
                                                     int* __restrict__ out) {
    int i = blockIdx.x * 256 + threadIdx.x;
    int4 v = ((const int4*)a)[i];
    out[i] = (v.x & 0xff) | ((v.y & 0xff) << 8) |
             ((v.z & 0xff) << 16) | ((v.w & 0xff) << 24);
}

// ---- pack b: int32 [K][N] -> int8 [N][K] (transpose via LDS tile) ----
__global__ __launch_bounds__(256) void pack_b_kernel(const int* __restrict__ b,
                                                     char* __restrict__ out) {
    __shared__ char tile[64][68];
    const int n0 = blockIdx.x * 64;
    const int k0 = blockIdx.y * 64;
    const int t  = threadIdx.x;
    const int tr  = t >> 4;
    const int tc4 = (t & 15) << 2;
#pragma unroll
    for (int j = 0; j < 4; ++j) {
        int row = tr + j * 16;
        int4 v = *(const int4*)&b[(size_t)(k0 + row) * N_DIM + n0 + tc4];
        tile[row][tc4 + 0] = (char)v.x;
        tile[row][tc4 + 1] = (char)v.y;
        tile[row][tc4 + 2] = (char)v.z;
        tile[row][tc4 + 3] = (char)v.w;
    }
    __syncthreads();
#pragma unroll
    for (int j = 0; j < 4; ++j) {
        int n = tr + j * 16;
        int pk = (tile[tc4 + 0][n] & 0xff) |
                 ((tile[tc4 + 1][n] & 0xff) << 8) |
                 ((tile[tc4 + 2][n] & 0xff) << 16) |
                 ((tile[tc4 + 3][n] & 0xff) << 24);
        *(int*)&out[(size_t)(n0 + n) * K_DIM + k0 + tc4] = pk;
    }
}

// ---- GEMM: 256x128 block, 4 waves, wave-tile 64x128 ----
// A-fragments load DIRECTLY global->VGPR: each wave owns 64 distinct A-rows,
// so A has zero intra-block reuse and LDS staging for it is a pure round-trip
// tax (the R4 profile-arithmetic shows LDS traffic binding at ~750-1130
// cyc/stage vs MFMA 653). Only B (reuse 4) goes through LDS: 16 KB/stage.
// A-loads for stage kt+1 issue after the barrier and retire during compute.
__global__ __launch_bounds__(256, 2) void gemm_i8_kernel(const char* __restrict__ A8,
                                                         const char* __restrict__ B8,
                                                         int* __restrict__ C) {
    __shared__ __align__(16) char Bs[2 * 128 * 64];   // [k64-half][n][64B]

    const int t    = threadIdx.x;
    const int bn   = blockIdx.x;
    const int bm   = blockIdx.y;
    const int lane = t & 63;
    const int wave = t >> 6;
    const int quad = lane >> 4;
    const int l16  = lane & 15;

    const int    mWave = bm * 256 + wave * 64;            // wave's first A-row
    const char*  aPtr  = A8 + (size_t)(mWave + l16) * K_DIM + quad * 16;
    const size_t bBase = (size_t)(bn * 128) * K_DIM;

    // B staging: 4 slots x 16B per thread
    const int sr = t >> 2;
    const int sc = (t & 3) << 4;

    int4v acc[4][8] = {};

    // A fragments for stage 0
    int4v af[2][4];
#pragma unroll
    for (int h = 0; h < 2; ++h)
#pragma unroll
        for (int mi = 0; mi < 4; ++mi)
            af[h][mi] = *(const int4v*)(aPtr + (size_t)mi * 16 * K_DIM + h * 64);

    for (int kt = 0; kt < K_DIM / BK; ++kt) {
        const int kOff = kt * BK;

        // stage B tile (16 KB) to LDS
#pragma unroll
        for (int s = 0; s < 4; ++s) {
            const int r = ((s & 1) << 6) + sr;
            const int f = s * 4096 + t * 16;
            gload16(B8 + bBase + (size_t)r * K_DIM + kOff + (s >> 1) * 64 + sc,
                    Bs + f);
        }
        __syncthreads();   // drains B staging (and any in-flight A prefetch)

        // prefetch A fragments for NEXT stage; they retire during the MFMAs
        const int kNext = (kt < K_DIM / BK - 1) ? kOff + BK : 0;
        int4v afn[2][4];
#pragma unroll
        for (int h = 0; h < 2; ++h)
#pragma unroll
            for (int mi = 0; mi < 4; ++mi)
                afn[h][mi] = *(const int4v*)(aPtr + (size_t)mi * 16 * K_DIM +
                                             kNext + h * 64);

#pragma unroll
        for (int h = 0; h < 2; ++h) {
            int4v bf[8];
#pragma unroll
            for (int ni = 0; ni < 8; ++ni)
                bf[ni] = *(const int4v*)&Bs[h * 8192 + (ni * 16 + l16) * 64 +
                                            quad * 16];
#pragma unroll
            for (int mi = 0; mi < 4; ++mi)
#pragma unroll
                for (int ni = 0; ni < 8; ++ni)
                    acc[mi][ni] = __builtin_amdgcn_mfma_i32_16x16x64_i8(
                        af[h][mi], bf[ni], acc[mi][ni], 0, 0, 0);
        }

        __syncthreads();   // Bs reads done before next stage overwrites

#pragma unroll
        for (int h = 0; h < 2; ++h)
#pragma unroll
            for (int mi = 0; mi < 4; ++mi)
                af[h][mi] = afn[h][mi];
    }

    // epilogue: C/D layout col=lane&15, row=4*quad+reg; saturate, store int32
    const int nB0 = bn * 128;
#pragma unroll
    for (int mi = 0; mi < 4; ++mi) {
#pragma unroll
        for (int ni = 0; ni < 8; ++ni) {
            const int col = nB0 + ni * 16 + l16;
#pragma unroll
            for (int r = 0; r < 4; ++r) {
                const int row = mWave + mi * 16 + quad * 4 + r;
                C[(size_t)row * N_DIM + col] = sat8(acc[mi][ni][r]);
            }
        }
    }
}

// ---- fallback (only if ws_size < 16MB): direct int32 GEMM, slow but correct ----
__global__ __launch_bounds__(256) void gemm_naive_kernel(const int* __restrict__ a,
                                                         const int* __restrict__ b,
                                                         int* __restrict__ C) {
    const int col = blockIdx.x * 256 + threadIdx.x;
    const int row = blockIdx.y;
    int acc = 0;
    for (int k = 0; k < K_DIM; ++k)
        acc += a[(size_t)row * K_DIM + k] * b[(size_t)k * N_DIM + col];
    C[(size_t)row * N_DIM + col] = sat8(acc);
}

extern "C" void kernel_launch(void* const* d_in, const int* in_sizes, int n_in,
                              void* d_out, int out_size, void* d_ws, size_t ws_size,
                              hipStream_t stream) {
    const int* a = (const int*)d_in[0];
    const int* b = (const int*)d_in[1];
    // alpha_row (d_in[2]) / alpha_col (d_in[3]) are unused in this variant.
    int* out = (int*)d_out;

    const size_t needed = 2 * (size_t)M_DIM * K_DIM;   // 16 MB packed operands
    if (ws_size < needed) {
        gemm_naive_kernel<<<dim3(N_DIM / 256, M_DIM), 256, 0, stream>>>(a, b, out);
        return;
    }

    char* A8 = (char*)d_ws;                          // 8 MB
    char* B8 = A8 + (size_t)M_DIM * K_DIM;           // 8 MB

    pack_a_kernel<<<(M_DIM * K_DIM / 4) / 256, 256, 0, stream>>>(a, (int*)A8);
    pack_b_kernel<<<dim3(N_DIM / 64, K_DIM / 64), 256, 0, stream>>>(b, B8);
    gemm_i8_kernel<<<dim3(N_DIM / 128, M_DIM / 256), 256, 0, stream>>>(A8, B8, out);
}